// Round 10
// baseline (102.758 us; speedup 1.0000x reference)
//
#include <hip/hip_runtime.h>

// Pfaffian of 128 gathered 128x128 skew-symmetric f32 matrices, Parlett-Reid
// LTL^T, one 256-thread block per matrix, 8x8 register sub-block per thread.
//
// NUMERICS LEDGER (rounds 0-9): np ref is the XLA-CPU f32 trajectory with
// FMA-fused rank-2 update:
//     tmp = fma(tau_i, col_j, A);  A' = fma(-col_i, tau_j, tmp)
// tau = IEEE f32 divide (__fdiv_rn), pf = __fmul_rn product in step order.
// Rounds 5-9 PASSED with absmax 0.0234375; this schedule must not change.
// (Within-step element update ORDER is freely permutable: the rank-2 update
// is elementwise-independent. Used below for publisher-first scheduling.)
//
// PERF LEDGER:
//   r5-r7 ~225 us: A spilled (dynamic indexing). r8: compile-time indices ->
//     50.6 us. r9: 1 barrier/step + dbuf + shfl pivot -> 47 us. VALUBusy
//     8.8% => ~256 of ~1650 cyc/step is VALU; the step time is the
//     PUBLISHER wave's serial chain (all-64-elem update, THEN shfl+fdiv+
//     writes) + a pointless per-step pivbuf ds_read on every wave for pf.
//   r10: (a) publisher-first ordering — update row a0 (8 elems), publish
//     tau; update col c0 (7), publish col; then the 49 rest: publisher LDS
//     writes overlap everyone's FMA tail. (b) pf off-path: pivots -> LDS
//     piv_hist[], thread 0 does the 64 ordered fmuls ONCE at the end.

#define POFF(i) ((i) + (((i) >> 5) << 2))   // 4-float pad every 32 floats

__global__ __launch_bounds__(256, 1) void pfaffian_kernel(
    const float* __restrict__ x,    // [128, 128]
    const float* __restrict__ F,    // [32640] packed strict lower tri of 256x256
    float* __restrict__ out)        // [128]
{
    const int b    = blockIdx.x;
    const int t    = threadIdx.x;
    const int lane = t & 63;
    const int wave = t >> 6;

    __shared__ int idx_sh[128];
    __shared__ int wtot[4];
    __shared__ __align__(16) float bufT[2][144];  // tau (padded, 0 on dead idx)
    __shared__ __align__(16) float bufC[2][144];  // col  (padded, 0 on dead idx)
    __shared__ float piv_hist[64];                // pivot of each step (off-path)

    // ---- occupancy -> sorted index list (certified rounds 0-9) ----
    const float xv  = x[b * 128 + (t & 127)];
    const bool  pos = xv > 0.0f;
    const bool  o   = (t < 128) ? pos : !pos;

    const unsigned long long m = __ballot(o);
    const int rank = __popcll(m & ((1ull << lane) - 1ull));
    if (lane == 63) wtot[wave] = rank + (o ? 1 : 0);
    __syncthreads();
    int off = 0;
#pragma unroll
    for (int w = 0; w < 4; ++w)
        if (w < wave) off += wtot[w];
    if (o) idx_sh[off + rank] = t;
    __syncthreads();

    // ---- 8x8 block ownership ----
    const int r8   = t >> 4;        // row group: rows [r8*8, r8*8+8)
    const int c8   = t & 15;        // col group: cols [c8*8, c8*8+8)
    const int row0 = r8 * 8;
    const int col0 = c8 * 8;
    const int prow = POFF(row0);
    const int pcol = POFF(col0);

    int ri[8], ci[8];
#pragma unroll
    for (int a = 0; a < 8; ++a) ri[a] = idx_sh[row0 + a];
#pragma unroll
    for (int c = 0; c < 8; ++c) ci[c] = idx_sh[col0 + c];

    // ---- gather A[a][c] = F_full[ri[a]][ci[c]] (all indices compile-time) ----
    float A[8][8];
#pragma unroll
    for (int a = 0; a < 8; ++a) {
        const int ii = ri[a];
#pragma unroll
        for (int c = 0; c < 8; ++c) {
            const int jj = ci[c];
            const int hi = ii > jj ? ii : jj;
            const int lo = ii > jj ? jj : ii;
            float v = (ii == jj) ? 0.0f : F[(hi * (hi - 1)) / 2 + lo];
            A[a][c] = (ii < jj) ? -v : v;
        }
    }

    // ---- seed step 0: pivot A[0][1] (owner t=0) -> piv_hist[0], then
    //      tau0/col0 into buf parity 0
    if (t == 0) piv_hist[0] = A[0][1];
    __syncthreads();
    {
        const float piv0 = piv_hist[0];
        if (r8 == 0) {               // tau publishers for step 0 (row 0)
            float v[8];
#pragma unroll
            for (int j = 0; j < 8; ++j) {
                const int cj = col0 + j;
                v[j] = (cj > 1) ? __fdiv_rn(A[0][j], piv0) : 0.0f;
            }
            *(float4*)&bufT[0][pcol]     = make_float4(v[0], v[1], v[2], v[3]);
            *(float4*)&bufT[0][pcol + 4] = make_float4(v[4], v[5], v[6], v[7]);
        }
        if (c8 == 0) {               // col publishers for step 0 (col 1)
            float v[8];
#pragma unroll
            for (int j = 0; j < 8; ++j) {
                const int rj = row0 + j;
                v[j] = (rj > 1) ? A[j][1] : 0.0f;
            }
            *(float4*)&bufC[0][prow]     = make_float4(v[0], v[1], v[2], v[3]);
            *(float4*)&bufC[0][prow + 4] = make_float4(v[4], v[5], v[6], v[7]);
        }
    }
    __syncthreads();

    // ---- 64 steps, ONE barrier each; s unrolled -> parity & indices static
    for (int ib = 0; ib < 16; ++ib) {
#pragma unroll
        for (int s = 0; s < 4; ++s) {
            const int i   = ib * 4 + s;
            const int k   = 8 * ib + 2 * s;
            const int kp1 = k + 1;
            const int p   = s & 1;            // == i & 1 (compile-time)
            const int q   = 1 - p;
            const int a0  = (2 * s + 2) & 7;  // in-block row of global row k+2
            const int c0  = (2 * s + 3) & 7;  // in-block col of global col k+3

            if (wave * 32 + 31 > kp1) {       // wave-uniform early-out
                // ---- load step-i vectors ----
                float4 tr0 = *(const float4*)&bufT[p][prow];
                float4 tr1 = *(const float4*)&bufT[p][prow + 4];
                float4 cr0 = *(const float4*)&bufC[p][prow];
                float4 cr1 = *(const float4*)&bufC[p][prow + 4];
                float4 tc0 = *(const float4*)&bufT[p][pcol];
                float4 tc1 = *(const float4*)&bufT[p][pcol + 4];
                float4 cc0 = *(const float4*)&bufC[p][pcol];
                float4 cc1 = *(const float4*)&bufC[p][pcol + 4];

                float tr[8] = {tr0.x, tr0.y, tr0.z, tr0.w, tr1.x, tr1.y, tr1.z, tr1.w};
                float cr[8] = {cr0.x, cr0.y, cr0.z, cr0.w, cr1.x, cr1.y, cr1.z, cr1.w};
                float tc[8] = {tc0.x, tc0.y, tc0.z, tc0.w, tc1.x, tc1.y, tc1.z, tc1.w};
                float cc[8] = {cc0.x, cc0.y, cc0.z, cc0.w, cc1.x, cc1.y, cc1.z, cc1.w};

                float ncr[8];
#pragma unroll
                for (int a = 0; a < 8; ++a) ncr[a] = -cr[a];

                // ---- (1) update row a0 first (publisher-critical) ----
#pragma unroll
                for (int c = 0; c < 8; ++c) {
                    const float tmp = __fmaf_rn(tr[a0], cc[c], A[a0][c]);
                    A[a0][c] = __fmaf_rn(ncr[a0], tc[c], tmp);
                }

                // ---- (2) tau publish for step i+1 (overlaps others' FMAs) ----
                if (i < 63) {
                    const int ntg = (k + 2) >> 3;
                    const int ncg = (k + 3) >> 3;
                    if (r8 == ntg) {
                        const int ownerLane = ((ntg << 4) + ncg) & 63;
                        const float newpiv = __shfl(A[a0][c0], ownerLane);
                        if (c8 == ncg) piv_hist[i + 1] = newpiv;  // off-path
                        float v[8];
#pragma unroll
                        for (int j = 0; j < 8; ++j) {
                            const int cj = col0 + j;
                            v[j] = (cj > k + 3) ? __fdiv_rn(A[a0][j], newpiv)
                                                : 0.0f;
                        }
                        *(float4*)&bufT[q][pcol]     = make_float4(v[0], v[1], v[2], v[3]);
                        *(float4*)&bufT[q][pcol + 4] = make_float4(v[4], v[5], v[6], v[7]);
                    }
                }

                // ---- (3) update col c0 (rows != a0) ----
#pragma unroll
                for (int a = 0; a < 8; ++a) {
                    if (a != a0) {
                        const float tmp = __fmaf_rn(tr[a], cc[c0], A[a][c0]);
                        A[a][c0] = __fmaf_rn(ncr[a], tc[c0], tmp);
                    }
                }

                // ---- (4) col publish for step i+1 ----
                if (i < 63) {
                    const int ncg = (k + 3) >> 3;
                    if (c8 == ncg) {
                        float v[8];
#pragma unroll
                        for (int j = 0; j < 8; ++j) {
                            const int rj = row0 + j;
                            v[j] = (rj > k + 3) ? A[j][c0] : 0.0f;
                        }
                        *(float4*)&bufC[q][prow]     = make_float4(v[0], v[1], v[2], v[3]);
                        *(float4*)&bufC[q][prow + 4] = make_float4(v[4], v[5], v[6], v[7]);
                    }
                }

                // ---- (5) remaining 49 elements ----
#pragma unroll
                for (int a = 0; a < 8; ++a) {
                    if (a != a0) {
#pragma unroll
                        for (int c = 0; c < 8; ++c) {
                            if (c != c0) {
                                const float tmp = __fmaf_rn(tr[a], cc[c], A[a][c]);
                                A[a][c] = __fmaf_rn(ncr[a], tc[c], tmp);
                            }
                        }
                    }
                }
            }
            __syncthreads();   // the ONLY barrier per step
        }
    }

    // ---- epilogue: ordered pivot product (one-time, off the step path) ----
    if (t == 0) {
        float pf = 1.0f;
#pragma unroll 8
        for (int i = 0; i < 64; ++i) pf = __fmul_rn(pf, piv_hist[i]);
        out[b] = pf;
    }
}

extern "C" void kernel_launch(void* const* d_in, const int* in_sizes, int n_in,
                              void* d_out, int out_size, void* d_ws, size_t ws_size,
                              hipStream_t stream) {
    const float* x = (const float*)d_in[0];   // [128*128]
    const float* F = (const float*)d_in[1];   // [32640]
    float* out     = (float*)d_out;           // [128]
    (void)in_sizes; (void)n_in; (void)out_size; (void)d_ws; (void)ws_size;

    pfaffian_kernel<<<128, 256, 0, stream>>>(x, F, out);
}

// Round 11
// 91.672 us; speedup vs baseline: 1.1209x; 1.1209x over previous
//
#include <hip/hip_runtime.h>

// Pfaffian of 128 gathered 128x128 skew-symmetric f32 matrices, Parlett-Reid
// LTL^T, one 512-thread block per matrix, 4x8 register sub-block per thread.
//
// NUMERICS LEDGER (rounds 0-10): np ref is the XLA-CPU f32 trajectory with
// FMA-fused rank-2 update:
//     tmp = fma(tau_r, col_c, A);  A' = fma(-col_r, tau_c, tmp)
// tau = IEEE f32 divide (__fdiv_rn), pf = __fmul_rn product in step order.
// Rounds 5-10 PASSED with absmax 0.0234375; the arithmetic graph (values,
// op kinds, per-element op order) must not change. Partitioning may.
//
// PERF LEDGER:
//   r5-r7 ~225us: A spilled (dynamic idx). r8: static idx -> 50.6us.
//   r9: 1 barrier/step + dbuf + shfl pivot -> 47us (barrier =~135cyc, NOT
//     the floor). r10: publisher-first ordering REGRESSED (52.5us, VGPR 76)
//     -> reverted; keep r9 body order + piv_hist epilogue.
//   r11: 256->512 threads/matrix (4x8 blocks). Per-wave FMA issue halves
//     (128 insts -> 64) and each SIMD now hosts 2 waves, so LDS latency /
//     publisher chain / barrier drain overlap across waves. At 1 wave/SIMD
//     (r9) there was ZERO latency hiding.

#define POFF(i) ((i) + (((i) >> 5) << 2))   // 4-float pad every 32 floats

__global__ __launch_bounds__(512) void pfaffian_kernel(
    const float* __restrict__ x,    // [128, 128]
    const float* __restrict__ F,    // [32640] packed strict lower tri of 256x256
    float* __restrict__ out)        // [128]
{
    const int b    = blockIdx.x;
    const int t    = threadIdx.x;
    const int lane = t & 63;
    const int wave = t >> 6;        // 0..7

    __shared__ int idx_sh[128];
    __shared__ int wtot[4];
    __shared__ __align__(16) float bufT[2][144];  // tau (padded, 0 on dead idx)
    __shared__ __align__(16) float bufC[2][144];  // col  (padded, 0 on dead idx)
    __shared__ float piv_hist[64];                // pivots (off the step path)

    // ---- occupancy -> sorted index list (waves 0-3 only; certified r0-r10)
    if (t < 256) {
        const float xv  = x[b * 128 + (t & 127)];
        const bool  pos = xv > 0.0f;
        const bool  o   = (t < 128) ? pos : !pos;

        const unsigned long long mm = __ballot(o);
        const int rank = __popcll(mm & ((1ull << lane) - 1ull));
        if (lane == 63) wtot[wave] = rank + (o ? 1 : 0);
        __syncthreads();
        int off = 0;
#pragma unroll
        for (int w = 0; w < 4; ++w)
            if (w < wave) off += wtot[w];
        if (o) idx_sh[off + rank] = t;
    } else {
        __syncthreads();   // matches the barrier inside the t<256 branch
    }
    __syncthreads();

    // ---- 4x8 block ownership ----
    const int rg   = t >> 4;        // row group 0..31: rows [rg*4, rg*4+4)
    const int cg   = t & 15;        // col group 0..15: cols [cg*8, cg*8+8)
    const int row0 = rg << 2;
    const int col0 = cg << 3;
    const int prow = POFF(row0);    // 16B-aligned, never crosses a pad
    const int pcol = POFF(col0);

    int ri[4], ci[8];
#pragma unroll
    for (int a = 0; a < 4; ++a) ri[a] = idx_sh[row0 + a];
#pragma unroll
    for (int c = 0; c < 8; ++c) ci[c] = idx_sh[col0 + c];

    // ---- gather A[a][c] = F_full[ri[a]][ci[c]] (all indices compile-time) ----
    float A[4][8];
#pragma unroll
    for (int a = 0; a < 4; ++a) {
        const int ii = ri[a];
#pragma unroll
        for (int c = 0; c < 8; ++c) {
            const int jj = ci[c];
            const int hi = ii > jj ? ii : jj;
            const int lo = ii > jj ? jj : ii;
            float v = (ii == jj) ? 0.0f : F[(hi * (hi - 1)) / 2 + lo];
            A[a][c] = (ii < jj) ? -v : v;
        }
    }

    // ---- seed step 0: pivot A[0][1] (owner t=0), tau0/col0 into parity 0 ----
    if (t == 0) piv_hist[0] = A[0][1];
    __syncthreads();
    {
        const float piv0 = piv_hist[0];
        if (rg == 0) {               // tau publishers (row 0), 16 threads
            float v[8];
#pragma unroll
            for (int j = 0; j < 8; ++j) {
                const int cj = col0 + j;
                v[j] = (cj > 1) ? __fdiv_rn(A[0][j], piv0) : 0.0f;
            }
            *(float4*)&bufT[0][pcol]     = make_float4(v[0], v[1], v[2], v[3]);
            *(float4*)&bufT[0][pcol + 4] = make_float4(v[4], v[5], v[6], v[7]);
        }
        if (cg == 0) {               // col publishers (col 1), 32 threads
            float v[4];
#pragma unroll
            for (int j = 0; j < 4; ++j) {
                const int rj = row0 + j;
                v[j] = (rj > 1) ? A[j][1] : 0.0f;
            }
            *(float4*)&bufC[0][prow] = make_float4(v[0], v[1], v[2], v[3]);
        }
    }
    __syncthreads();

    // ---- 64 steps, ONE barrier each; s unrolled -> parity & indices static
    for (int ib = 0; ib < 16; ++ib) {
#pragma unroll
        for (int s = 0; s < 4; ++s) {
            const int i   = ib * 4 + s;
            const int k   = 8 * ib + 2 * s;
            const int kp1 = k + 1;
            const int p   = s & 1;              // == i & 1 (compile-time)
            const int q   = 1 - p;
            const int ka  = (2 * s + 2) & 3;    // in-block row of global row k+2
            const int kc  = (2 * s + 3) & 7;    // in-block col of global col k+3

            // wave w owns rows [16w, 16w+16): alive iff top row survives
            if (wave * 16 + 15 > kp1) {
                // ---- load step-i vectors (broadcast/<=2-way reads, free) ----
                float4 trv = *(const float4*)&bufT[p][prow];
                float4 crv = *(const float4*)&bufC[p][prow];
                float4 tc0 = *(const float4*)&bufT[p][pcol];
                float4 tc1 = *(const float4*)&bufT[p][pcol + 4];
                float4 cc0 = *(const float4*)&bufC[p][pcol];
                float4 cc1 = *(const float4*)&bufC[p][pcol + 4];

                float tr[4] = {trv.x, trv.y, trv.z, trv.w};
                float cr[4] = {crv.x, crv.y, crv.z, crv.w};
                float tc[8] = {tc0.x, tc0.y, tc0.z, tc0.w, tc1.x, tc1.y, tc1.z, tc1.w};
                float cc[8] = {cc0.x, cc0.y, cc0.z, cc0.w, cc1.x, cc1.y, cc1.z, cc1.w};

                float ncr[4];
#pragma unroll
                for (int a = 0; a < 4; ++a) ncr[a] = -cr[a];

                // ---- rank-2 update (dead entries: zeros-trick identity) ----
#pragma unroll
                for (int a = 0; a < 4; ++a) {
#pragma unroll
                    for (int c = 0; c < 8; ++c) {
                        const float tmp = __fmaf_rn(tr[a], cc[c], A[a][c]);
                        A[a][c] = __fmaf_rn(ncr[a], tc[c], tmp);
                    }
                }

                // ---- publish step i+1 into parity q (post-update values) ----
                if (i < 63) {
                    const int ntr = (k + 2) >> 2;   // next tau row group
                    const int ncg = (k + 3) >> 3;   // next col group
                    if (rg == ntr) {
                        // pivot forwarded in-register within this wave
                        const int ownerLane = ((ntr << 4) + ncg) & 63;
                        const float newpiv = __shfl(A[ka][kc], ownerLane);
                        if (cg == ncg) piv_hist[i + 1] = newpiv;  // off-path
                        float v[8];
#pragma unroll
                        for (int j = 0; j < 8; ++j) {
                            const int cj = col0 + j;
                            v[j] = (cj > k + 3) ? __fdiv_rn(A[ka][j], newpiv)
                                                : 0.0f;
                        }
                        *(float4*)&bufT[q][pcol]     = make_float4(v[0], v[1], v[2], v[3]);
                        *(float4*)&bufT[q][pcol + 4] = make_float4(v[4], v[5], v[6], v[7]);
                    }
                    if (cg == ncg) {
                        float v[4];
#pragma unroll
                        for (int j = 0; j < 4; ++j) {
                            const int rj = row0 + j;
                            v[j] = (rj > k + 3) ? A[j][kc] : 0.0f;
                        }
                        *(float4*)&bufC[q][prow] = make_float4(v[0], v[1], v[2], v[3]);
                    }
                }
            }
            __syncthreads();   // the ONLY barrier per step
        }
    }

    // ---- epilogue: ordered pivot product (one-time, off the step path) ----
    if (t == 0) {
        float pf = 1.0f;
#pragma unroll 8
        for (int i = 0; i < 64; ++i) pf = __fmul_rn(pf, piv_hist[i]);
        out[b] = pf;
    }
}

extern "C" void kernel_launch(void* const* d_in, const int* in_sizes, int n_in,
                              void* d_out, int out_size, void* d_ws, size_t ws_size,
                              hipStream_t stream) {
    const float* x = (const float*)d_in[0];   // [128*128]
    const float* F = (const float*)d_in[1];   // [32640]
    float* out     = (float*)d_out;           // [128]
    (void)in_sizes; (void)n_in; (void)out_size; (void)d_ws; (void)ws_size;

    pfaffian_kernel<<<128, 512, 0, stream>>>(x, F, out);
}

// Round 12
// 79.519 us; speedup vs baseline: 1.2922x; 1.1528x over previous
//
#include <hip/hip_runtime.h>

// Pfaffian of 128 gathered 128x128 skew-symmetric f32 matrices, Parlett-Reid
// LTL^T. One 512-thread block per matrix; PANEL scheme: 4 steps per panel,
// 2 barriers per panel (0.5/step vs r11's 1/step).
//
// NUMERICS LEDGER (rounds 0-11): np ref is the XLA-CPU f32 trajectory:
//     tmp = fma(tau_r, col_c, A);  A' = fma(-col_r, tau_c, tmp)
// tau = __fdiv_rn(row_k, piv), pf = __fmul_rn in step order. Rounds 5-11
// PASSED with absmax 0.0234375 — bit-identical trajectory preserved here:
// same per-element FMA pairs in step order, same divides, same pivots.
// Dead indices staged/published as exact 0.0f (identity FMAs on elements
// that are never read again — same invariant as r9-r11).
//
// PERF LEDGER: r8 static idx 50.6us -> r9 1 barrier/step 47us -> r11 512thr
// 41us (VALUBusy 10%: per-step publisher serial chain + barrier is the
// floor of the 1-barrier/step shape). r12: crew/bulk panel split — wave 0
// chains 4 steps wave-synchronously (readlane pivot, no barriers),
// publishes 4 tau/col vector pairs; bulk applies all 4 rank-2 updates with
// batched LDS reads; bulk stages next panel's rows/cols from its
// post-update registers.

#define RL(v, l) __int_as_float(__builtin_amdgcn_readlane(__float_as_int(v), (l)))

__global__ __launch_bounds__(512) void pfaffian_kernel(
    const float* __restrict__ x,    // [128, 128]
    const float* __restrict__ F,    // [32640] packed strict lower tri of 256x256
    float* __restrict__ out)        // [128]
{
    const int b    = blockIdx.x;
    const int t    = threadIdx.x;
    const int lane = t & 63;
    const int wave = t >> 6;        // 0..7

    __shared__ int idx_sh[128];
    __shared__ int wtot[4];
    __shared__ __align__(16) float tauLDS[4][128];  // per panel-step tau (0 on dead)
    __shared__ __align__(16) float colLDS[4][128];  // per panel-step col (0 on dead)
    __shared__ __align__(16) float rS[4][128];      // next-panel rows k0,k0+2,k0+4,k0+6
    __shared__ __align__(16) float cS[4][128];      // next-panel cols k0+1,+3,+5,+7

    // ---- occupancy -> sorted index list (certified r0-r11) ----
    if (t < 256) {
        const float xv  = x[b * 128 + (t & 127)];
        const bool  pos = xv > 0.0f;
        const bool  o   = (t < 128) ? pos : !pos;
        const unsigned long long mm = __ballot(o);
        const int rank = __popcll(mm & ((1ull << lane) - 1ull));
        if (lane == 63) wtot[wave] = rank + (o ? 1 : 0);
        __syncthreads();
        int off = 0;
#pragma unroll
        for (int w = 0; w < 4; ++w)
            if (w < wave) off += wtot[w];
        if (o) idx_sh[off + rank] = t;
    } else {
        __syncthreads();   // matches the barrier inside the t<256 branch
    }
    __syncthreads();

    // ---- 4x8 block ownership (as r11) ----
    const int rg   = t >> 4;        // rows [rg*4, rg*4+4)
    const int cg   = t & 15;        // cols [cg*8, cg*8+8)
    const int row0 = rg << 2;
    const int col0 = cg << 3;

    int ri[4], ci[8];
#pragma unroll
    for (int a = 0; a < 4; ++a) ri[a] = idx_sh[row0 + a];
#pragma unroll
    for (int c = 0; c < 8; ++c) ci[c] = idx_sh[col0 + c];

    float A[4][8];
#pragma unroll
    for (int a = 0; a < 4; ++a) {
        const int ii = ri[a];
#pragma unroll
        for (int c = 0; c < 8; ++c) {
            const int jj = ci[c];
            const int hi = ii > jj ? ii : jj;
            const int lo = ii > jj ? jj : ii;
            float v = (ii == jj) ? 0.0f : F[(hi * (hi - 1)) / 2 + lo];
            A[a][c] = (ii < jj) ? -v : v;
        }
    }

    // stage panel rows/cols (rgbase = first rg of the panel's rows,
    // cgbase = cg owning the panel's cols). Rows k0,k0+2 from rgbase
    // (ka=0,2), k0+4,k0+6 from rgbase+1 (ka=0,2); cols k0+1..k0+7 odd.
    auto stage_next = [&](int rgbase, int cgbase) {
        if (rg == rgbase) {
            *(float4*)&rS[0][col0]     = make_float4(A[0][0], A[0][1], A[0][2], A[0][3]);
            *(float4*)&rS[0][col0 + 4] = make_float4(A[0][4], A[0][5], A[0][6], A[0][7]);
            *(float4*)&rS[1][col0]     = make_float4(A[2][0], A[2][1], A[2][2], A[2][3]);
            *(float4*)&rS[1][col0 + 4] = make_float4(A[2][4], A[2][5], A[2][6], A[2][7]);
        }
        if (rg == rgbase + 1) {
            *(float4*)&rS[2][col0]     = make_float4(A[0][0], A[0][1], A[0][2], A[0][3]);
            *(float4*)&rS[2][col0 + 4] = make_float4(A[0][4], A[0][5], A[0][6], A[0][7]);
            *(float4*)&rS[3][col0]     = make_float4(A[2][0], A[2][1], A[2][2], A[2][3]);
            *(float4*)&rS[3][col0 + 4] = make_float4(A[2][4], A[2][5], A[2][6], A[2][7]);
        }
        if (cg == cgbase) {
            *(float4*)&cS[0][row0] = make_float4(A[0][1], A[1][1], A[2][1], A[3][1]);
            *(float4*)&cS[1][row0] = make_float4(A[0][3], A[1][3], A[2][3], A[3][3]);
            *(float4*)&cS[2][row0] = make_float4(A[0][5], A[1][5], A[2][5], A[3][5]);
            *(float4*)&cS[3][row0] = make_float4(A[0][7], A[1][7], A[2][7], A[3][7]);
        }
    };
    stage_next(0, 0);   // panel 0 rows/cols from gathered values

    // ---- 16 panels x 4 steps; 2 barriers per panel ----
    float pf = 1.0f;
    for (int P = 0; P < 16; ++P) {
        __syncthreads();   // B1: staging visible to crew; bulk done with tau/colLDS

        if (wave == 0) {
            // ---- crew: lane owns indices g0=2*lane, g1=g0+1 of each vector ----
            const int g0 = lane << 1;
            const int g1 = g0 + 1;
            float R[4][2], C[4][2], TAU[4][2], CV[4][2];
#pragma unroll
            for (int j = 0; j < 4; ++j) {
                const float2 rv = *(const float2*)&rS[j][g0];
                const float2 cv = *(const float2*)&cS[j][g0];
                R[j][0] = rv.x; R[j][1] = rv.y;
                C[j][0] = cv.x; C[j][1] = cv.y;
            }
#pragma unroll
            for (int j = 0; j < 4; ++j) {
                const int k = 8 * P + 2 * j;
                // pivot = R[j] at col k+1 -> lane (k+1)>>1 = 4P+j, elem 1
                const float piv = RL(R[j][1], 4 * P + j);
                pf = __fmul_rn(pf, piv);      // step order; uniform in wave

                TAU[j][0] = (g0 > k + 1) ? __fdiv_rn(R[j][0], piv) : 0.0f;
                TAU[j][1] = (g1 > k + 1) ? __fdiv_rn(R[j][1], piv) : 0.0f;
                CV[j][0]  = (g0 > k + 1) ? C[j][0] : 0.0f;
                CV[j][1]  = (g1 > k + 1) ? C[j][1] : 0.0f;

                *(float2*)&tauLDS[j][g0] = make_float2(TAU[j][0], TAU[j][1]);
                *(float2*)&colLDS[j][g0] = make_float2(CV[j][0], CV[j][1]);

                // update later panel vectors with step j (bit-exact pair order)
#pragma unroll
                for (int j2 = j + 1; j2 < 4; ++j2) {
                    const int ls = 4 * P + j2;          // lane holding idx 8P+2j2(+1)
                    const float tau_r = RL(TAU[j][0], ls);   // tau[row 8P+2j2]
                    const float col_r = RL(CV[j][0], ls);    // col[row 8P+2j2]
                    R[j2][0] = __fmaf_rn(-col_r, TAU[j][0],
                               __fmaf_rn(tau_r, CV[j][0], R[j2][0]));
                    R[j2][1] = __fmaf_rn(-col_r, TAU[j][1],
                               __fmaf_rn(tau_r, CV[j][1], R[j2][1]));
                    const float tau_c = RL(TAU[j][1], ls);   // tau[col 8P+2j2+1]
                    const float col_c = RL(CV[j][1], ls);    // col[col 8P+2j2+1]
                    C[j2][0] = __fmaf_rn(-CV[j][0], tau_c,
                               __fmaf_rn(TAU[j][0], col_c, C[j2][0]));
                    C[j2][1] = __fmaf_rn(-CV[j][1], tau_c,
                               __fmaf_rn(TAU[j][1], col_c, C[j2][1]));
                }
            }
        }
        __syncthreads();   // B2: tau/colLDS visible to bulk

        // ---- bulk: apply 4 rank-2 updates; wave alive iff top row survives ----
        if (2 * wave + 1 > P) {
#pragma unroll
            for (int j = 0; j < 4; ++j) {
                const float4 trv = *(const float4*)&tauLDS[j][row0];
                const float4 crv = *(const float4*)&colLDS[j][row0];
                const float4 t0v = *(const float4*)&tauLDS[j][col0];
                const float4 t1v = *(const float4*)&tauLDS[j][col0 + 4];
                const float4 c0v = *(const float4*)&colLDS[j][col0];
                const float4 c1v = *(const float4*)&colLDS[j][col0 + 4];
                const float tr[4] = {trv.x, trv.y, trv.z, trv.w};
                const float cr[4] = {crv.x, crv.y, crv.z, crv.w};
                const float tc[8] = {t0v.x, t0v.y, t0v.z, t0v.w,
                                     t1v.x, t1v.y, t1v.z, t1v.w};
                const float cc[8] = {c0v.x, c0v.y, c0v.z, c0v.w,
                                     c1v.x, c1v.y, c1v.z, c1v.w};
#pragma unroll
                for (int a = 0; a < 4; ++a) {
#pragma unroll
                    for (int c = 0; c < 8; ++c) {
                        A[a][c] = __fmaf_rn(-cr[a], tc[c],
                                  __fmaf_rn(tr[a], cc[c], A[a][c]));
                    }
                }
            }
            if (P < 15) stage_next(2 * P + 2, P + 1);  // post-update values
        }
    }

    if (t == 0) out[b] = pf;
}

extern "C" void kernel_launch(void* const* d_in, const int* in_sizes, int n_in,
                              void* d_out, int out_size, void* d_ws, size_t ws_size,
                              hipStream_t stream) {
    const float* x = (const float*)d_in[0];   // [128*128]
    const float* F = (const float*)d_in[1];   // [32640]
    float* out     = (float*)d_out;           // [128]
    (void)in_sizes; (void)n_in; (void)out_size; (void)d_ws; (void)ws_size;

    pfaffian_kernel<<<128, 512, 0, stream>>>(x, F, out);
}

// Round 13
// 76.098 us; speedup vs baseline: 1.3503x; 1.0450x over previous
//
#include <hip/hip_runtime.h>

// Pfaffian of 128 gathered 128x128 skew-symmetric f32 matrices, Parlett-Reid
// LTL^T. One 512-thread block per matrix. LOOK-AHEAD PANEL PIPELINE:
// crew (wave 0) computes panel P+1's tau/col vectors WHILE bulk (waves 1-7)
// applies panel P — one barrier per window, 15 windows.
//
// NUMERICS LEDGER (rounds 0-12): np ref is the XLA-CPU f32 trajectory:
//     tmp = fma(tau_r, col_c, A);  A' = fma(-col_r, tau_c, tmp)
// tau = __fdiv_rn(row_k, piv), pf = __fmul_rn in step order. Rounds 5-12
// PASSED with absmax 0.0234375 (bit-stable fingerprint). Preserved here:
// crew's register pre-update of panel-(P+1) vectors applies the SAME fma
// pairs in step order with the SAME zero-masked tau/col values bulk uses
// (zeros-trick identity on dead indices), so the trajectory is bit-identical.
//
// PERF LEDGER: r8 static idx 50.6us -> r9 1 barrier/step 47 -> r11 512thr
// 41 -> r12 4-step panels (crew THEN bulk, 2 barriers) ~29us. r12's crew
// (~1-2k cyc) sat on the critical path in SERIES with bulk. r13: crew and
// bulk overlap in one barrier window; bulk alive = (2*wave > P) — panels
// 14/15 bulk is dead code (elements never staged/read after crew takes
// their vectors); wave 0 never bulks (its rows only feed panel-0/1 vectors,
// staged raw in the prologue).
//
// Buffer schedule (all parity double-buffered, reads/writes separated by
// the window barrier):
//   tauLDS/colLDS set s: panel Pn with Pn&1==s. Crew W_P writes (P+1)&1;
//     bulk W_P reads P&1.
//   rS/cS set s: panel Pn's vectors, staged in W_{Pn-2} (prologue for 0,1).
//     Bulk W_P stages panel P+2 -> set P&1; crew W_P reads panel P+1 ->
//     set (P+1)&1.

#define RL(v, l) __int_as_float(__builtin_amdgcn_readlane(__float_as_int(v), (l)))

__global__ __launch_bounds__(512) void pfaffian_kernel(
    const float* __restrict__ x,    // [128, 128]
    const float* __restrict__ F,    // [32640] packed strict lower tri of 256x256
    float* __restrict__ out)        // [128]
{
    const int b    = blockIdx.x;
    const int t    = threadIdx.x;
    const int lane = t & 63;
    const int wave = t >> 6;        // 0..7

    __shared__ int idx_sh[128];
    __shared__ int wtot[4];
    __shared__ __align__(16) float tauLDS[2][4][128];
    __shared__ __align__(16) float colLDS[2][4][128];
    __shared__ __align__(16) float rS[2][4][128];   // panel row vecs k0,k0+2,k0+4,k0+6
    __shared__ __align__(16) float cS[2][4][128];   // panel col vecs k0+1,+3,+5,+7

    // ---- occupancy -> sorted index list (certified r0-r12) ----
    if (t < 256) {
        const float xv  = x[b * 128 + (t & 127)];
        const bool  pos = xv > 0.0f;
        const bool  o   = (t < 128) ? pos : !pos;
        const unsigned long long mm = __ballot(o);
        const int rank = __popcll(mm & ((1ull << lane) - 1ull));
        if (lane == 63) wtot[wave] = rank + (o ? 1 : 0);
        __syncthreads();
        int off = 0;
#pragma unroll
        for (int w = 0; w < 4; ++w)
            if (w < wave) off += wtot[w];
        if (o) idx_sh[off + rank] = t;
    } else {
        __syncthreads();   // matches the barrier inside the t<256 branch
    }
    __syncthreads();

    // ---- 4x8 block ownership ----
    const int rg   = t >> 4;        // rows [rg*4, rg*4+4)
    const int cg   = t & 15;        // cols [cg*8, cg*8+8)
    const int row0 = rg << 2;
    const int col0 = cg << 3;

    int ri[4], ci[8];
#pragma unroll
    for (int a = 0; a < 4; ++a) ri[a] = idx_sh[row0 + a];
#pragma unroll
    for (int c = 0; c < 8; ++c) ci[c] = idx_sh[col0 + c];

    float A[4][8];
#pragma unroll
    for (int a = 0; a < 4; ++a) {
        const int ii = ri[a];
#pragma unroll
        for (int c = 0; c < 8; ++c) {
            const int jj = ci[c];
            const int hi = ii > jj ? ii : jj;
            const int lo = ii > jj ? jj : ii;
            float v = (ii == jj) ? 0.0f : F[(hi * (hi - 1)) / 2 + lo];
            A[a][c] = (ii < jj) ? -v : v;
        }
    }

    // stage panel Pn (rgbase = 2*Pn, cgbase = Pn) into set st
    auto stage = [&](int Pn, int st) {
        const int rgbase = 2 * Pn;
        if (rg == rgbase) {
            *(float4*)&rS[st][0][col0]     = make_float4(A[0][0], A[0][1], A[0][2], A[0][3]);
            *(float4*)&rS[st][0][col0 + 4] = make_float4(A[0][4], A[0][5], A[0][6], A[0][7]);
            *(float4*)&rS[st][1][col0]     = make_float4(A[2][0], A[2][1], A[2][2], A[2][3]);
            *(float4*)&rS[st][1][col0 + 4] = make_float4(A[2][4], A[2][5], A[2][6], A[2][7]);
        }
        if (rg == rgbase + 1) {
            *(float4*)&rS[st][2][col0]     = make_float4(A[0][0], A[0][1], A[0][2], A[0][3]);
            *(float4*)&rS[st][2][col0 + 4] = make_float4(A[0][4], A[0][5], A[0][6], A[0][7]);
            *(float4*)&rS[st][3][col0]     = make_float4(A[2][0], A[2][1], A[2][2], A[2][3]);
            *(float4*)&rS[st][3][col0 + 4] = make_float4(A[2][4], A[2][5], A[2][6], A[2][7]);
        }
        if (cg == Pn) {
            *(float4*)&cS[st][0][row0] = make_float4(A[0][1], A[1][1], A[2][1], A[3][1]);
            *(float4*)&cS[st][1][row0] = make_float4(A[0][3], A[1][3], A[2][3], A[3][3]);
            *(float4*)&cS[st][2][row0] = make_float4(A[0][5], A[1][5], A[2][5], A[3][5]);
            *(float4*)&cS[st][3][row0] = make_float4(A[0][7], A[1][7], A[2][7], A[3][7]);
        }
    };
    stage(0, 0);   // panel 0 raw
    stage(1, 1);   // panel 1 raw
    __syncthreads();

    float pf = 1.0f;
    float TAUp[4][2], CVp[4][2];   // crew: previous panel's tau/col (registers)

    // crew for panel Pn: pre-update with panel Pn-1 (if pre), chain, publish
    auto crew = [&](int Pn, bool pre) {
        const int sv = Pn & 1;
        const int g0 = lane << 1;
        const int g1 = g0 + 1;
        float R[4][2], C[4][2];
#pragma unroll
        for (int j = 0; j < 4; ++j) {
            const float2 rv = *(const float2*)&rS[sv][j][g0];
            const float2 cv = *(const float2*)&cS[sv][j][g0];
            R[j][0] = rv.x; R[j][1] = rv.y;
            C[j][0] = cv.x; C[j][1] = cv.y;
        }
        if (pre) {
            // apply panel Pn-1 (TAUp/CVp) to these 8 vectors, bit-exact with
            // bulk's schedule (zeros at dead indices -> identity)
#pragma unroll
            for (int jp = 0; jp < 4; ++jp) {
#pragma unroll
                for (int a = 0; a < 4; ++a) {
                    const int la = 4 * Pn + a;   // lane of row 8Pn+2a / col 8Pn+2a+1
                    const float tau_r = RL(TAUp[jp][0], la);
                    const float col_r = RL(CVp[jp][0], la);
                    R[a][0] = __fmaf_rn(-col_r, TAUp[jp][0],
                              __fmaf_rn(tau_r, CVp[jp][0], R[a][0]));
                    R[a][1] = __fmaf_rn(-col_r, TAUp[jp][1],
                              __fmaf_rn(tau_r, CVp[jp][1], R[a][1]));
                    const float tau_c = RL(TAUp[jp][1], la);
                    const float col_c = RL(CVp[jp][1], la);
                    C[a][0] = __fmaf_rn(-CVp[jp][0], tau_c,
                              __fmaf_rn(TAUp[jp][0], col_c, C[a][0]));
                    C[a][1] = __fmaf_rn(-CVp[jp][1], tau_c,
                              __fmaf_rn(TAUp[jp][1], col_c, C[a][1]));
                }
            }
        }
        float TAU[4][2], CV[4][2];
#pragma unroll
        for (int j = 0; j < 4; ++j) {
            const int k = 8 * Pn + 2 * j;
            const float piv = RL(R[j][1], 4 * Pn + j);
            pf = __fmul_rn(pf, piv);          // step order
            TAU[j][0] = (g0 > k + 1) ? __fdiv_rn(R[j][0], piv) : 0.0f;
            TAU[j][1] = (g1 > k + 1) ? __fdiv_rn(R[j][1], piv) : 0.0f;
            CV[j][0]  = (g0 > k + 1) ? C[j][0] : 0.0f;
            CV[j][1]  = (g1 > k + 1) ? C[j][1] : 0.0f;
            *(float2*)&tauLDS[sv][j][g0] = make_float2(TAU[j][0], TAU[j][1]);
            *(float2*)&colLDS[sv][j][g0] = make_float2(CV[j][0], CV[j][1]);
            // look-ahead: update later panel vectors with step j (r12-certified)
#pragma unroll
            for (int j2 = j + 1; j2 < 4; ++j2) {
                const int ls = 4 * Pn + j2;
                const float tau_r = RL(TAU[j][0], ls);
                const float col_r = RL(CV[j][0], ls);
                R[j2][0] = __fmaf_rn(-col_r, TAU[j][0],
                           __fmaf_rn(tau_r, CV[j][0], R[j2][0]));
                R[j2][1] = __fmaf_rn(-col_r, TAU[j][1],
                           __fmaf_rn(tau_r, CV[j][1], R[j2][1]));
                const float tau_c = RL(TAU[j][1], ls);
                const float col_c = RL(CV[j][1], ls);
                C[j2][0] = __fmaf_rn(-CV[j][0], tau_c,
                           __fmaf_rn(TAU[j][0], col_c, C[j2][0]));
                C[j2][1] = __fmaf_rn(-CV[j][1], tau_c,
                           __fmaf_rn(TAU[j][1], col_c, C[j2][1]));
            }
        }
#pragma unroll
        for (int j = 0; j < 4; ++j) {
            TAUp[j][0] = TAU[j][0]; TAUp[j][1] = TAU[j][1];
            CVp[j][0]  = CV[j][0];  CVp[j][1]  = CV[j][1];
        }
    };

    // ---- prologue: crew computes panel 0 from raw staged vectors ----
    if (wave == 0) crew(0, false);
    __syncthreads();

    // ---- 15 windows, ONE barrier each: bulk panel P || crew panel P+1 ----
    for (int P = 0; P < 15; ++P) {
        if (wave >= 1 && 2 * wave > P) {
            const int sp = P & 1;
#pragma unroll
            for (int j = 0; j < 4; ++j) {
                const float4 trv = *(const float4*)&tauLDS[sp][j][row0];
                const float4 crv = *(const float4*)&colLDS[sp][j][row0];
                const float4 t0v = *(const float4*)&tauLDS[sp][j][col0];
                const float4 t1v = *(const float4*)&tauLDS[sp][j][col0 + 4];
                const float4 c0v = *(const float4*)&colLDS[sp][j][col0];
                const float4 c1v = *(const float4*)&colLDS[sp][j][col0 + 4];
                const float tr[4] = {trv.x, trv.y, trv.z, trv.w};
                const float cr[4] = {crv.x, crv.y, crv.z, crv.w};
                const float tc[8] = {t0v.x, t0v.y, t0v.z, t0v.w,
                                     t1v.x, t1v.y, t1v.z, t1v.w};
                const float cc[8] = {c0v.x, c0v.y, c0v.z, c0v.w,
                                     c1v.x, c1v.y, c1v.z, c1v.w};
#pragma unroll
                for (int a = 0; a < 4; ++a) {
#pragma unroll
                    for (int c = 0; c < 8; ++c) {
                        A[a][c] = __fmaf_rn(-cr[a], tc[c],
                                  __fmaf_rn(tr[a], cc[c], A[a][c]));
                    }
                }
            }
            if (P <= 13) stage(P + 2, P & 1);   // updated through P
        }
        if (wave == 0) crew(P + 1, true);       // panels 1..15
        __syncthreads();
    }

    if (t == 0) out[b] = pf;
}

extern "C" void kernel_launch(void* const* d_in, const int* in_sizes, int n_in,
                              void* d_out, int out_size, void* d_ws, size_t ws_size,
                              hipStream_t stream) {
    const float* x = (const float*)d_in[0];   // [128*128]
    const float* F = (const float*)d_in[1];   // [32640]
    float* out     = (float*)d_out;           // [128]
    (void)in_sizes; (void)n_in; (void)out_size; (void)d_ws; (void)ws_size;

    pfaffian_kernel<<<128, 512, 0, stream>>>(x, F, out);
}